// Round 12
// baseline (409.583 us; speedup 1.0000x reference)
//
#include <hip/hip_runtime.h>

#define H 128
#define CAP 8192   // per-bucket capacity; mean fill ~4096, sigma ~64

typedef __attribute__((ext_vector_type(8))) short bf16x8;
typedef __attribute__((ext_vector_type(4))) float f32x4;

__device__ __forceinline__ unsigned short f2bf(float f) {
    unsigned u = __float_as_uint(f);
    u += 0x7FFFu + ((u >> 16) & 1u);
    return (unsigned short)(u >> 16);
}
__device__ __forceinline__ float bflo(unsigned v) { return __uint_as_float(v << 16); }
__device__ __forceinline__ float bfhi(unsigned v) { return __uint_as_float(v & 0xFFFF0000u); }

// ---- scatter edges into fixed-capacity dst-buckets ----------------------
// bucket b covers dst nodes [b*256, b*256+256); record = src | dst_low8<<24
__global__ void __launch_bounds__(256) k_scatter(const int* __restrict__ ei,
        int* __restrict__ gcur, int* __restrict__ tmp_e, int E) {
    __shared__ int hist[512], base[512], fill[512];
    int blk = blockIdx.x, t = threadIdx.x;
    int chunk = (E + gridDim.x - 1) / gridDim.x;
    int c0 = blk * chunk;
    int c1 = c0 + chunk; if (c1 > E) c1 = E;
    hist[t] = 0; hist[t + 256] = 0;
    __syncthreads();
    for (int e = c0 + t; e < c1; e += 256)
        atomicAdd(&hist[ei[E + e] >> 8], 1);
    __syncthreads();
    for (int u = t; u < 512; u += 256) {
        int h = hist[u];
        base[u] = h ? atomicAdd(&gcur[u], h) : 0;
        fill[u] = 0;
    }
    __syncthreads();
    for (int e = c0 + t; e < c1; e += 256) {
        int d = ei[E + e], s = ei[e];
        int bb = d >> 8;
        int p = base[bb] + atomicAdd(&fill[bb], 1);
        if (p < CAP) tmp_e[bb * CAP + p] = s | ((d & 255) << 24);
    }
}

// merged per-bucket: count + scan -> rpse {start,end}, dinv; scatter csrc
__global__ void __launch_bounds__(256) k_csrAB(const int* __restrict__ tmp_e,
        const int* __restrict__ gcur, int2* __restrict__ rpse,
        float* __restrict__ dinv, int* __restrict__ csrc, int N) {
    __shared__ int cnt[256];
    __shared__ int sh[256];
    __shared__ int fill[256];
    int b = blockIdx.x, t = threadIdx.x;
    int e0 = b * CAP;
    int tot = gcur[b]; if (tot > CAP) tot = CAP;
    int e1 = e0 + tot;
    cnt[t] = 0;
    __syncthreads();
    for (int e = e0 + t; e < e1; e += 256)
        atomicAdd(&cnt[(unsigned)tmp_e[e] >> 24], 1);
    __syncthreads();
    int v = cnt[t];
    sh[t] = v;
    __syncthreads();
    for (int off = 1; off < 256; off <<= 1) {
        int u = (t >= off) ? sh[t - off] : 0;
        __syncthreads();
        sh[t] += u;
        __syncthreads();
    }
    int mystart = e0 + sh[t] - v;
    fill[t] = mystart;
    int gid = (b << 8) + t;
    if (gid < N) {
        rpse[gid] = make_int2(mystart, mystart + v);
        dinv[gid] = rsqrtf((float)(v + 1));
    }
    __syncthreads();
    for (int e = e0 + t; e < e1; e += 256) {
        int te = tmp_e[e];
        int l = (unsigned)te >> 24;
        int p = atomicAdd(&fill[l], 1);
        csrc[p] = te & 0xFFFFFF;
    }
}

// ---- merged prep: xs scale (+zero row) AND weight prep ------------------
__global__ void k_prep(const float* __restrict__ x, const float* __restrict__ dinv,
                       unsigned* __restrict__ xs, int N,
                       const float* __restrict__ W, const float* __restrict__ b,
                       const float* __restrict__ r3w, const float* __restrict__ r3b,
                       const float* __restrict__ r2w, const float* __restrict__ r2b,
                       unsigned short* __restrict__ Wt, unsigned short* __restrict__ WRb,
                       float* __restrict__ bias2) {
    int gi = blockIdx.x * blockDim.x + threadIdx.x;
    int total = N * 64;
    if (gi < total) {
        float d = dinv[gi >> 6];
        float2 v = ((const float2*)x)[gi];
        xs[gi] = (unsigned)f2bf(d * v.x) | ((unsigned)f2bf(d * v.y) << 16);
        return;
    }
    if (gi < total + 64) { xs[gi] = 0; return; }
    int idx = gi - (total + 64);
    if (idx < 114688) {
        int k = idx >> 14;
        int f = (idx >> 7) & 127;
        int h = idx & 127;
        Wt[(k << 14) + (h << 7) + f] = f2bf(W[idx]);
        return;
    }
    int idx2 = idx - 114688;
    if (idx2 < 14336) {
        int j = idx2 & 7;
        int lane = (idx2 >> 3) & 63;
        int kk = (idx2 >> 9) & 3;
        int k = idx2 >> 11;
        int c = lane & 15;
        int off = ((lane >> 4) << 3) + j;
        int f = kk * 32 + (off >> 1) + ((off & 1) << 4);
        int ck = (k < 5) ? 3 : 2;
        float s = 0.0f;
        if (c < ck) {
            const float* R = (k < 5) ? (r3w + (size_t)(k * 3 + c) * H)
                                     : (r2w + (size_t)((k - 5) * 2 + c) * H);
            const float* Wk = W + (k << 14) + (f << 7);
            for (int h = 0; h < H; ++h) s += Wk[h] * R[h];
        }
        WRb[idx2] = f2bf(s);
    } else if (idx2 < 14336 + 32) {
        int c32 = idx2 - 14336;
        int k = c32 >> 2, c = c32 & 3;
        int ck = (k < 5) ? 3 : 2;
        float t = 0.0f;
        if (c < ck) {
            const float* R = (k < 5) ? (r3w + (size_t)(k * 3 + c) * H)
                                     : (r2w + (size_t)((k - 5) * 2 + c) * H);
            const float* bk = b + k * H;
            for (int h = 0; h < H; ++h) t += bk[h] * R[h];
            t += (k < 5) ? r3b[k * 3 + c] : r2b[(k - 5) * 2 + c];
        }
        bias2[c32] = t;
    }
}

// ---- pack: us[j] = bf16(uall[j])  (uall already dinv-scaled by k_gemm) --
__global__ void k_upack(const float* __restrict__ u, unsigned* __restrict__ us, int N) {
    int i = blockIdx.x * blockDim.x + threadIdx.x;
    int total = N * 16;
    if (i < total) {
        float2 v = ((const float2*)u)[i];
        us[i] = (unsigned)f2bf(v.x) | ((unsigned)f2bf(v.y) << 16);
    } else if (i < total + 16) {
        us[i] = 0;
    }
}

__device__ __forceinline__ void acc8(float2* a, const uint4 v) {
    a[0].x += bflo(v.x); a[0].y += bfhi(v.x);
    a[1].x += bflo(v.y); a[1].y += bfhi(v.y);
    a[2].x += bflo(v.z); a[2].y += bfhi(v.z);
    a[3].x += bflo(v.w); a[3].y += bfhi(v.w);
}

// ---- aggregation 1: px[i] = dinv[i] * (sum_j xs[j] + xs[i]) -------------
__global__ void __launch_bounds__(256) k_px(const unsigned* __restrict__ xs,
        const int2* __restrict__ rpse, const int* __restrict__ csrc,
        const float* __restrict__ dinv, unsigned* __restrict__ pxb, int N) {
    int lane = threadIdx.x & 63;
    int wv = threadIdx.x >> 6;
    int i = blockIdx.x * 4 + wv;
    if (i >= N) return;
    int grp = lane >> 4, sub = lane & 15;
    const unsigned* xbs = xs + sub * 4;
    int2 se = rpse[i];
    int s = se.x, e = se.y;
    float2 a0[4] = {{0.f,0.f},{0.f,0.f},{0.f,0.f},{0.f,0.f}};
    float2 a1[4] = {{0.f,0.f},{0.f,0.f},{0.f,0.f},{0.f,0.f}};
    for (int base = s; base < e; base += 64) {
        int el = base + lane;
        int j_l = (el < e) ? csrc[el] : N;
        int cnt = e - base; if (cnt > 64) cnt = 64;
        for (int t = 0; t < cnt; t += 16) {
            int jj0 = __shfl(j_l, t + grp);
            int jj1 = __shfl(j_l, t + 4 + grp);
            int jj2 = __shfl(j_l, t + 8 + grp);
            int jj3 = __shfl(j_l, t + 12 + grp);
            const uint4 v0 = *(const uint4*)(xbs + (size_t)jj0 * 64);
            const uint4 v1 = *(const uint4*)(xbs + (size_t)jj1 * 64);
            const uint4 v2 = *(const uint4*)(xbs + (size_t)jj2 * 64);
            const uint4 v3 = *(const uint4*)(xbs + (size_t)jj3 * 64);
            acc8(a0, v0); acc8(a1, v1); acc8(a0, v2); acc8(a1, v3);
        }
    }
    float acc[8];
#pragma unroll
    for (int r = 0; r < 4; ++r) {
        acc[2 * r] = a0[r].x + a1[r].x;
        acc[2 * r + 1] = a0[r].y + a1[r].y;
    }
#pragma unroll
    for (int r = 0; r < 8; ++r) {
        acc[r] += __shfl_xor(acc[r], 16);
        acc[r] += __shfl_xor(acc[r], 32);
    }
    if (grp == 0) {
        const uint4 v = *(const uint4*)(xbs + (size_t)i * 64);
        float d = dinv[i];
        uint4 o;
        o.x = (unsigned)f2bf(d * (acc[0] + bflo(v.x))) | ((unsigned)f2bf(d * (acc[1] + bfhi(v.x))) << 16);
        o.y = (unsigned)f2bf(d * (acc[2] + bflo(v.y))) | ((unsigned)f2bf(d * (acc[3] + bfhi(v.y))) << 16);
        o.z = (unsigned)f2bf(d * (acc[4] + bflo(v.z))) | ((unsigned)f2bf(d * (acc[5] + bfhi(v.z))) << 16);
        o.w = (unsigned)f2bf(d * (acc[6] + bflo(v.w))) | ((unsigned)f2bf(d * (acc[7] + bfhi(v.w))) << 16);
        *(uint4*)(pxb + (size_t)i * 64 + sub * 4) = o;
    }
}

// ---- GEMM: uall = dinv * ((relu(px@Wk + bk)) @ WR_k) --------------------
__global__ void __launch_bounds__(256, 2) k_gemm(const unsigned short* __restrict__ pxb,
        const unsigned short* __restrict__ Wt, const float* __restrict__ gb,
        const unsigned short* __restrict__ WRb, const float* __restrict__ dinv,
        float* __restrict__ uall, int N) {
    __shared__ __align__(16) unsigned short Bs[128 * 136];
    __shared__ __align__(16) unsigned h1w[4][2560];
    int k = blockIdx.y;
    int wv = threadIdx.x >> 6;
    int lane = threadIdx.x & 63;
    int quad = lane >> 4, l16 = lane & 15;

    {
        const unsigned short* src = Wt + (k << 14);
        int t = threadIdx.x;
#pragma unroll
        for (int i = 0; i < 8; ++i) {
            int li = i * 256 + t;
            int f = li >> 4, seg = li & 15;
            *(bf16x8*)(Bs + f * 136 + seg * 8) = *(const bf16x8*)(src + f * 128 + seg * 8);
        }
    }
    __syncthreads();

    unsigned* wl = &h1w[wv][0];
    int rowbase = blockIdx.x * 512 + wv * 32;

    bf16x8 af[2][2][4];
    {
        int rb0 = rowbase;
#pragma unroll
        for (int rb = 0; rb < 2; ++rb) {
            int r = rb0 + rb * 16 + l16;
            if (r >= N) r = N - 1;
#pragma unroll
            for (int kk = 0; kk < 4; ++kk)
                af[0][rb][kk] = *(const bf16x8*)(pxb + (size_t)r * H + kk * 32 + quad * 8);
        }
    }

    float bi[4][2];
#pragma unroll
    for (int p = 0; p < 4; ++p) {
        bi[p][0] = gb[k * H + 32 * p + l16];
        bi[p][1] = gb[k * H + 32 * p + 16 + l16];
    }
    bf16x8 bw[4];
#pragma unroll
    for (int kk = 0; kk < 4; ++kk)
        bw[kk] = *(const bf16x8*)(WRb + (size_t)((k * 4 + kk) * 64 + lane) * 8);

    for (int t = 0; t < 4; ++t) {
        if (t < 3) {
            int rb0 = rowbase + (t + 1) * 128;
#pragma unroll
            for (int rb = 0; rb < 2; ++rb) {
                int r = rb0 + rb * 16 + l16;
                if (r >= N) r = N - 1;
#pragma unroll
                for (int kk = 0; kk < 4; ++kk)
                    af[(t + 1) & 1][rb][kk] = *(const bf16x8*)(pxb + (size_t)r * H + kk * 32 + quad * 8);
            }
        }
        int row0 = rowbase + t * 128;
#pragma unroll
        for (int p = 0; p < 4; ++p) {
            f32x4 cacc[2][2] = {};
#pragma unroll
            for (int kk = 0; kk < 4; ++kk) {
                bf16x8 b0 = *(const bf16x8*)(Bs + (32 * p + l16) * 136 + kk * 32 + quad * 8);
                bf16x8 b1 = *(const bf16x8*)(Bs + (32 * p + 16 + l16) * 136 + kk * 32 + quad * 8);
#pragma unroll
                for (int rb = 0; rb < 2; ++rb) {
                    cacc[rb][0] = __builtin_amdgcn_mfma_f32_16x16x32_bf16(af[t & 1][rb][kk], b0, cacc[rb][0], 0, 0, 0);
                    cacc[rb][1] = __builtin_amdgcn_mfma_f32_16x16x32_bf16(af[t & 1][rb][kk], b1, cacc[rb][1], 0, 0, 0);
                }
            }
#pragma unroll
            for (int rb = 0; rb < 2; ++rb)
#pragma unroll
                for (int r = 0; r < 4; ++r) {
                    float lo = fmaxf(cacc[rb][0][r] + bi[p][0], 0.0f);
                    float hi = fmaxf(cacc[rb][1][r] + bi[p][1], 0.0f);
                    unsigned pk = (unsigned)f2bf(lo) | ((unsigned)f2bf(hi) << 16);
                    wl[(p * 32 + rb * 16 + quad * 4 + r) * 20 + l16] = pk;
                }
        }
        f32x4 u0 = {}, u1 = {};
#pragma unroll
        for (int kk = 0; kk < 4; ++kk) {
            bf16x8 a0 = *(const bf16x8*)(wl + (kk * 32 + l16) * 20 + quad * 4);
            bf16x8 a1 = *(const bf16x8*)(wl + (kk * 32 + 16 + l16) * 20 + quad * 4);
            u0 = __builtin_amdgcn_mfma_f32_16x16x32_bf16(a0, bw[kk], u0, 0, 0, 0);
            u1 = __builtin_amdgcn_mfma_f32_16x16x32_bf16(a1, bw[kk], u1, 0, 0, 0);
        }
        if (l16 < 4) {
#pragma unroll
            for (int r = 0; r < 4; ++r) {
                int ra = row0 + quad * 4 + r;
                int rb2 = ra + 16;
                if (ra < N) uall[(size_t)ra * 32 + k * 4 + l16] = u0[r] * dinv[ra];
                if (rb2 < N) uall[(size_t)rb2 * 32 + k * 4 + l16] = u1[r] * dinv[rb2];
            }
        }
    }
}

// ---- aggregation 2 + softmax: v = dinv[i]*(sum us[j] + us[i]) + bias ----
// us[j] = dinv[j]*u[j]; so d*(sum + us[i]) = sum norm_e*u[j] + invdeg*u[i]
__global__ void __launch_bounds__(256) k_out(const unsigned* __restrict__ us,
        const int2* __restrict__ rpse, const int* __restrict__ csrc,
        const float* __restrict__ dinv, const float* __restrict__ bias2,
        float* __restrict__ out, int N) {
    int lane = threadIdx.x & 63;
    int wv = threadIdx.x >> 6;
    int i = blockIdx.x * 4 + wv;
    if (i >= N) return;
    int grp = lane >> 2, sub = lane & 3;
    const unsigned* usb = us + sub * 4;
    int2 se = rpse[i];
    int s = se.x, e = se.y;
    float2 a0[4] = {{0.f,0.f},{0.f,0.f},{0.f,0.f},{0.f,0.f}};
    float2 a1[4] = {{0.f,0.f},{0.f,0.f},{0.f,0.f},{0.f,0.f}};
    for (int base = s; base < e; base += 64) {
        int el = base + lane;
        int j_l = (el < e) ? csrc[el] : N;
        int cnt = e - base; if (cnt > 64) cnt = 64;
        for (int t = 0; t < cnt; t += 32) {
            int jj0 = __shfl(j_l, t + grp);
            int jj1 = __shfl(j_l, t + 16 + grp);
            const uint4 v0 = *(const uint4*)(usb + (size_t)jj0 * 16);
            const uint4 v1 = *(const uint4*)(usb + (size_t)jj1 * 16);
            acc8(a0, v0); acc8(a1, v1);
        }
    }
    float acc[8];
#pragma unroll
    for (int r = 0; r < 4; ++r) {
        acc[2 * r] = a0[r].x + a1[r].x;
        acc[2 * r + 1] = a0[r].y + a1[r].y;
    }
#pragma unroll
    for (int r = 0; r < 8; ++r) {
        acc[r] += __shfl_xor(acc[r], 4);
        acc[r] += __shfl_xor(acc[r], 8);
        acc[r] += __shfl_xor(acc[r], 16);
        acc[r] += __shfl_xor(acc[r], 32);
    }
    if (grp == 0) {
        const uint4 sv = *(const uint4*)(usb + (size_t)i * 16);
        float d = dinv[i];
        float4 bA = *(const float4*)(bias2 + sub * 8);
        float4 bB = *(const float4*)(bias2 + sub * 8 + 4);
        float w0 = d * (acc[0] + bflo(sv.x)) + bA.x;
        float w1 = d * (acc[1] + bfhi(sv.x)) + bA.y;
        float w2 = d * (acc[2] + bflo(sv.y)) + bA.z;
        float w4 = d * (acc[4] + bflo(sv.z)) + bB.x;
        float w5 = d * (acc[5] + bfhi(sv.z)) + bB.y;
        float w6 = d * (acc[6] + bflo(sv.w)) + bB.z;
        auto wr = [&](int b, float v0, float v1, float v2) {
            int ck = (b < 5) ? 3 : 2;
            float mx = fmaxf(v0, v1);
            if (ck == 3) mx = fmaxf(mx, v2);
            float e0 = __expf(v0 - mx), e1 = __expf(v1 - mx);
            float e2 = (ck == 3) ? __expf(v2 - mx) : 0.0f;
            float inv = 1.0f / (e0 + e1 + e2);
            size_t bb = (b < 5) ? (size_t)b * 3 * N + (size_t)i * 3
                                : (size_t)15 * N + (size_t)(b - 5) * 2 * N + (size_t)i * 2;
            out[bb] = e0 * inv;
            out[bb + 1] = e1 * inv;
            if (ck == 3) out[bb + 2] = e2 * inv;
        };
        wr(sub * 2, w0, w1, w2);
        if (sub < 3) wr(sub * 2 + 1, w4, w5, w6);
    }
}

// ---- launch -------------------------------------------------------------
extern "C" void kernel_launch(void* const* d_in, const int* in_sizes, int n_in,
                              void* d_out, int out_size, void* d_ws, size_t ws_size,
                              hipStream_t stream) {
    (void)n_in; (void)out_size; (void)ws_size;
    const float* x   = (const float*)d_in[0];
    const int*   ei  = (const int*)d_in[1];
    const float* gw  = (const float*)d_in[2];
    const float* gb  = (const float*)d_in[3];
    const float* r3w = (const float*)d_in[4];
    const float* r3b = (const float*)d_in[5];
    const float* r2w = (const float*)d_in[6];
    const float* r2b = (const float*)d_in[7];
    float* out = (float*)d_out;
    int N = in_sizes[0] / H;   // 100000
    int E = in_sizes[1] / 2;   // 1600000
    int NB = (N + 255) >> 8;   // 391 buckets

    char* p = (char*)d_ws;
    auto alloc = [&](size_t bytes) {
        char* q = p;
        p += (bytes + 255) & ~(size_t)255;
        return q;
    };
    unsigned*       xs     = (unsigned*)alloc((size_t)(N + 1) * 64 * 4);  // scaled x bf16 + zero row
    unsigned*       pxb    = (unsigned*)alloc((size_t)N * 64 * 4);
    unsigned short* Wt     = (unsigned short*)alloc((size_t)7 * 16384 * 2);
    unsigned short* WRb    = (unsigned short*)alloc((size_t)14336 * 2);
    float*          bias2  = (float*)alloc(32 * 4);
    int*            gcur   = (int*)alloc(512 * 4);
    int*            tmp_e  = (int*)alloc((size_t)NB * CAP * 4);
    int2*           rpse   = (int2*)alloc((size_t)N * 8);
    float*          dinv   = (float*)alloc((size_t)N * 4);
    int*            csrc   = (int*)alloc((size_t)NB * CAP * 4);
    float*          uall   = (float*)alloc((size_t)N * 32 * 4);           // fp32, dinv-scaled
    unsigned*       usb    = (unsigned*)alloc((size_t)(N + 1) * 16 * 4);  // bf16 + zero row

    hipMemsetAsync(gcur, 0, 512 * 4, stream);
    k_scatter<<<256, 256, 0, stream>>>(ei, gcur, tmp_e, E);
    k_csrAB<<<NB, 256, 0, stream>>>(tmp_e, gcur, rpse, dinv, csrc, N);
    int prep_threads = N * 64 + 64 + 114688 + 14368;
    k_prep<<<(prep_threads + 255) / 256, 256, 0, stream>>>(x, dinv, xs, N,
            gw, gb, r3w, r3b, r2w, r2b, Wt, WRb, bias2);
    k_px<<<(N + 3) / 4, 256, 0, stream>>>(xs, rpse, csrc, dinv, pxb, N);
    dim3 gg((N + 511) / 512, 7);
    k_gemm<<<gg, 256, 0, stream>>>((const unsigned short*)pxb, Wt, gb, WRb, dinv, uall, N);
    k_upack<<<(N * 16 + 16 + 255) / 256, 256, 0, stream>>>(uall, usb, N);
    k_out<<<(N + 3) / 4, 256, 0, stream>>>(usb, rpse, csrc, dinv, bias2, out, N);
}

// Round 13
// 303.154 us; speedup vs baseline: 1.3511x; 1.3511x over previous
//
#include <hip/hip_runtime.h>

#define H 128
#define CAP 8192   // per-bucket capacity; mean fill ~4096, sigma ~64

typedef __attribute__((ext_vector_type(8))) short bf16x8;
typedef __attribute__((ext_vector_type(4))) float f32x4;

__device__ __forceinline__ unsigned short f2bf(float f) {
    unsigned u = __float_as_uint(f);
    u += 0x7FFFu + ((u >> 16) & 1u);
    return (unsigned short)(u >> 16);
}
__device__ __forceinline__ float bflo(unsigned v) { return __uint_as_float(v << 16); }
__device__ __forceinline__ float bfhi(unsigned v) { return __uint_as_float(v & 0xFFFF0000u); }

// ---- scatter edges into fixed-capacity dst-buckets ----------------------
// bucket b covers dst nodes [b*256, b*256+256); record = src | dst_low8<<24
__global__ void __launch_bounds__(256) k_scatter(const int* __restrict__ ei,
        int* __restrict__ gcur, int* __restrict__ tmp_e, int E) {
    __shared__ int hist[512], base[512], fill[512];
    int blk = blockIdx.x, t = threadIdx.x;
    int chunk = (E + gridDim.x - 1) / gridDim.x;
    int c0 = blk * chunk;
    int c1 = c0 + chunk; if (c1 > E) c1 = E;
    hist[t] = 0; hist[t + 256] = 0;
    __syncthreads();
    for (int e = c0 + t; e < c1; e += 256)
        atomicAdd(&hist[ei[E + e] >> 8], 1);
    __syncthreads();
    for (int u = t; u < 512; u += 256) {
        int h = hist[u];
        base[u] = h ? atomicAdd(&gcur[u], h) : 0;
        fill[u] = 0;
    }
    __syncthreads();
    for (int e = c0 + t; e < c1; e += 256) {
        int d = ei[E + e], s = ei[e];
        int bb = d >> 8;
        int p = base[bb] + atomicAdd(&fill[bb], 1);
        if (p < CAP) tmp_e[bb * CAP + p] = s | ((d & 255) << 24);
    }
}

// merged per-bucket: count + scan -> rpse {start,end}, dinv; scatter csrc
__global__ void __launch_bounds__(256) k_csrAB(const int* __restrict__ tmp_e,
        const int* __restrict__ gcur, int2* __restrict__ rpse,
        float* __restrict__ dinv, int* __restrict__ csrc, int N) {
    __shared__ int cnt[256];
    __shared__ int sh[256];
    __shared__ int fill[256];
    int b = blockIdx.x, t = threadIdx.x;
    int e0 = b * CAP;
    int tot = gcur[b]; if (tot > CAP) tot = CAP;
    int e1 = e0 + tot;
    cnt[t] = 0;
    __syncthreads();
    for (int e = e0 + t; e < e1; e += 256)
        atomicAdd(&cnt[(unsigned)tmp_e[e] >> 24], 1);
    __syncthreads();
    int v = cnt[t];
    sh[t] = v;
    __syncthreads();
    for (int off = 1; off < 256; off <<= 1) {
        int u = (t >= off) ? sh[t - off] : 0;
        __syncthreads();
        sh[t] += u;
        __syncthreads();
    }
    int mystart = e0 + sh[t] - v;
    fill[t] = mystart;
    int gid = (b << 8) + t;
    if (gid < N) {
        rpse[gid] = make_int2(mystart, mystart + v);
        dinv[gid] = rsqrtf((float)(v + 1));
    }
    __syncthreads();
    for (int e = e0 + t; e < e1; e += 256) {
        int te = tmp_e[e];
        int l = (unsigned)te >> 24;
        int p = atomicAdd(&fill[l], 1);
        csrc[p] = te & 0xFFFFFF;
    }
}

// ---- merged prep: xs scale (+zero row) AND weight prep ------------------
__global__ void k_prep(const float* __restrict__ x, const float* __restrict__ dinv,
                       unsigned* __restrict__ xs, int N,
                       const float* __restrict__ W, const float* __restrict__ b,
                       const float* __restrict__ r3w, const float* __restrict__ r3b,
                       const float* __restrict__ r2w, const float* __restrict__ r2b,
                       unsigned short* __restrict__ Wt, unsigned short* __restrict__ WRb,
                       float* __restrict__ bias2) {
    int gi = blockIdx.x * blockDim.x + threadIdx.x;
    int total = N * 64;
    if (gi < total) {
        float d = dinv[gi >> 6];
        float2 v = ((const float2*)x)[gi];
        xs[gi] = (unsigned)f2bf(d * v.x) | ((unsigned)f2bf(d * v.y) << 16);
        return;
    }
    if (gi < total + 64) { xs[gi] = 0; return; }
    int idx = gi - (total + 64);
    if (idx < 114688) {
        int k = idx >> 14;
        int f = (idx >> 7) & 127;
        int h = idx & 127;
        Wt[(k << 14) + (h << 7) + f] = f2bf(W[idx]);
        return;
    }
    int idx2 = idx - 114688;
    if (idx2 < 14336) {
        int j = idx2 & 7;
        int lane = (idx2 >> 3) & 63;
        int kk = (idx2 >> 9) & 3;
        int k = idx2 >> 11;
        int c = lane & 15;
        int off = ((lane >> 4) << 3) + j;
        int f = kk * 32 + (off >> 1) + ((off & 1) << 4);
        int ck = (k < 5) ? 3 : 2;
        float s = 0.0f;
        if (c < ck) {
            const float* R = (k < 5) ? (r3w + (size_t)(k * 3 + c) * H)
                                     : (r2w + (size_t)((k - 5) * 2 + c) * H);
            const float* Wk = W + (k << 14) + (f << 7);
            for (int h = 0; h < H; ++h) s += Wk[h] * R[h];
        }
        WRb[idx2] = f2bf(s);
    } else if (idx2 < 14336 + 32) {
        int c32 = idx2 - 14336;
        int k = c32 >> 2, c = c32 & 3;
        int ck = (k < 5) ? 3 : 2;
        float t = 0.0f;
        if (c < ck) {
            const float* R = (k < 5) ? (r3w + (size_t)(k * 3 + c) * H)
                                     : (r2w + (size_t)((k - 5) * 2 + c) * H);
            const float* bk = b + k * H;
            for (int h = 0; h < H; ++h) t += bk[h] * R[h];
            t += (k < 5) ? r3b[k * 3 + c] : r2b[(k - 5) * 2 + c];
        }
        bias2[c32] = t;
    }
}

// ---- prep: us[j] = bf16(dinv[j] * u[j]); zero row at index N ------------
__global__ void k_uscale(const float* __restrict__ u, const float* __restrict__ dinv,
                         unsigned* __restrict__ us, int N) {
    int i = blockIdx.x * blockDim.x + threadIdx.x;
    int total = N * 16;
    if (i < total) {
        float d = dinv[i >> 4];
        float2 v = ((const float2*)u)[i];
        us[i] = (unsigned)f2bf(d * v.x) | ((unsigned)f2bf(d * v.y) << 16);
    } else if (i < total + 16) {
        us[i] = 0;
    }
}

__device__ __forceinline__ void acc8(float2* a, const uint4 v) {
    a[0].x += bflo(v.x); a[0].y += bfhi(v.x);
    a[1].x += bflo(v.y); a[1].y += bfhi(v.y);
    a[2].x += bflo(v.z); a[2].y += bfhi(v.z);
    a[3].x += bflo(v.w); a[3].y += bfhi(v.w);
}

// ---- aggregation 1: px[i] = dinv[i] * (sum_j xs[j] + xs[i]) -------------
__global__ void __launch_bounds__(256) k_px(const unsigned* __restrict__ xs,
        const int2* __restrict__ rpse, const int* __restrict__ csrc,
        const float* __restrict__ dinv, unsigned* __restrict__ pxb, int N) {
    int lane = threadIdx.x & 63;
    int wv = threadIdx.x >> 6;
    int i = blockIdx.x * 4 + wv;
    if (i >= N) return;
    int grp = lane >> 4, sub = lane & 15;
    const unsigned* xbs = xs + sub * 4;
    int2 se = rpse[i];
    int s = se.x, e = se.y;
    float2 a0[4] = {{0.f,0.f},{0.f,0.f},{0.f,0.f},{0.f,0.f}};
    float2 a1[4] = {{0.f,0.f},{0.f,0.f},{0.f,0.f},{0.f,0.f}};
    for (int base = s; base < e; base += 64) {
        int el = base + lane;
        int j_l = (el < e) ? csrc[el] : N;
        int cnt = e - base; if (cnt > 64) cnt = 64;
        for (int t = 0; t < cnt; t += 16) {
            int jj0 = __shfl(j_l, t + grp);
            int jj1 = __shfl(j_l, t + 4 + grp);
            int jj2 = __shfl(j_l, t + 8 + grp);
            int jj3 = __shfl(j_l, t + 12 + grp);
            const uint4 v0 = *(const uint4*)(xbs + (size_t)jj0 * 64);
            const uint4 v1 = *(const uint4*)(xbs + (size_t)jj1 * 64);
            const uint4 v2 = *(const uint4*)(xbs + (size_t)jj2 * 64);
            const uint4 v3 = *(const uint4*)(xbs + (size_t)jj3 * 64);
            acc8(a0, v0); acc8(a1, v1); acc8(a0, v2); acc8(a1, v3);
        }
    }
    float acc[8];
#pragma unroll
    for (int r = 0; r < 4; ++r) {
        acc[2 * r] = a0[r].x + a1[r].x;
        acc[2 * r + 1] = a0[r].y + a1[r].y;
    }
#pragma unroll
    for (int r = 0; r < 8; ++r) {
        acc[r] += __shfl_xor(acc[r], 16);
        acc[r] += __shfl_xor(acc[r], 32);
    }
    if (grp == 0) {
        const uint4 v = *(const uint4*)(xbs + (size_t)i * 64);
        float d = dinv[i];
        uint4 o;
        o.x = (unsigned)f2bf(d * (acc[0] + bflo(v.x))) | ((unsigned)f2bf(d * (acc[1] + bfhi(v.x))) << 16);
        o.y = (unsigned)f2bf(d * (acc[2] + bflo(v.y))) | ((unsigned)f2bf(d * (acc[3] + bfhi(v.y))) << 16);
        o.z = (unsigned)f2bf(d * (acc[4] + bflo(v.z))) | ((unsigned)f2bf(d * (acc[5] + bfhi(v.z))) << 16);
        o.w = (unsigned)f2bf(d * (acc[6] + bflo(v.w))) | ((unsigned)f2bf(d * (acc[7] + bfhi(v.w))) << 16);
        *(uint4*)(pxb + (size_t)i * 64 + sub * 4) = o;
    }
}

// ---- GEMM: uall = (relu(px@Wk + bk)) @ WR_k -----------------------------
// PROVEN-FAST FORM (R8/R10): LDS-staged B, store-only epilogue. Do NOT add
// anything to the epilogue (R7 pack, R12 dinv-mul both triggered 15x HBM
// write amplification + L3 thrash).
__global__ void __launch_bounds__(256, 2) k_gemm(const unsigned short* __restrict__ pxb,
        const unsigned short* __restrict__ Wt, const float* __restrict__ gb,
        const unsigned short* __restrict__ WRb, float* __restrict__ uall, int N) {
    __shared__ __align__(16) unsigned short Bs[128 * 136];
    __shared__ __align__(16) unsigned h1w[4][2560];
    int k = blockIdx.y;
    int wv = threadIdx.x >> 6;
    int lane = threadIdx.x & 63;
    int quad = lane >> 4, l16 = lane & 15;

    {
        const unsigned short* src = Wt + (k << 14);
        int t = threadIdx.x;
#pragma unroll
        for (int i = 0; i < 8; ++i) {
            int li = i * 256 + t;
            int f = li >> 4, seg = li & 15;
            *(bf16x8*)(Bs + f * 136 + seg * 8) = *(const bf16x8*)(src + f * 128 + seg * 8);
        }
    }
    __syncthreads();

    unsigned* wl = &h1w[wv][0];
    int rowbase = blockIdx.x * 512 + wv * 32;

    bf16x8 af[2][2][4];
    {
        int rb0 = rowbase;
#pragma unroll
        for (int rb = 0; rb < 2; ++rb) {
            int r = rb0 + rb * 16 + l16;
            if (r >= N) r = N - 1;
#pragma unroll
            for (int kk = 0; kk < 4; ++kk)
                af[0][rb][kk] = *(const bf16x8*)(pxb + (size_t)r * H + kk * 32 + quad * 8);
        }
    }

    float bi[4][2];
#pragma unroll
    for (int p = 0; p < 4; ++p) {
        bi[p][0] = gb[k * H + 32 * p + l16];
        bi[p][1] = gb[k * H + 32 * p + 16 + l16];
    }
    bf16x8 bw[4];
#pragma unroll
    for (int kk = 0; kk < 4; ++kk)
        bw[kk] = *(const bf16x8*)(WRb + (size_t)((k * 4 + kk) * 64 + lane) * 8);

    for (int t = 0; t < 4; ++t) {
        if (t < 3) {
            int rb0 = rowbase + (t + 1) * 128;
#pragma unroll
            for (int rb = 0; rb < 2; ++rb) {
                int r = rb0 + rb * 16 + l16;
                if (r >= N) r = N - 1;
#pragma unroll
                for (int kk = 0; kk < 4; ++kk)
                    af[(t + 1) & 1][rb][kk] = *(const bf16x8*)(pxb + (size_t)r * H + kk * 32 + quad * 8);
            }
        }
        int row0 = rowbase + t * 128;
#pragma unroll
        for (int p = 0; p < 4; ++p) {
            f32x4 cacc[2][2] = {};
#pragma unroll
            for (int kk = 0; kk < 4; ++kk) {
                bf16x8 b0 = *(const bf16x8*)(Bs + (32 * p + l16) * 136 + kk * 32 + quad * 8);
                bf16x8 b1 = *(const bf16x8*)(Bs + (32 * p + 16 + l16) * 136 + kk * 32 + quad * 8);
#pragma unroll
                for (int rb = 0; rb < 2; ++rb) {
                    cacc[rb][0] = __builtin_amdgcn_mfma_f32_16x16x32_bf16(af[t & 1][rb][kk], b0, cacc[rb][0], 0, 0, 0);
                    cacc[rb][1] = __builtin_amdgcn_mfma_f32_16x16x32_bf16(af[t & 1][rb][kk], b1, cacc[rb][1], 0, 0, 0);
                }
            }
#pragma unroll
            for (int rb = 0; rb < 2; ++rb)
#pragma unroll
                for (int r = 0; r < 4; ++r) {
                    float lo = fmaxf(cacc[rb][0][r] + bi[p][0], 0.0f);
                    float hi = fmaxf(cacc[rb][1][r] + bi[p][1], 0.0f);
                    unsigned pk = (unsigned)f2bf(lo) | ((unsigned)f2bf(hi) << 16);
                    wl[(p * 32 + rb * 16 + quad * 4 + r) * 20 + l16] = pk;
                }
        }
        f32x4 u0 = {}, u1 = {};
#pragma unroll
        for (int kk = 0; kk < 4; ++kk) {
            bf16x8 a0 = *(const bf16x8*)(wl + (kk * 32 + l16) * 20 + quad * 4);
            bf16x8 a1 = *(const bf16x8*)(wl + (kk * 32 + 16 + l16) * 20 + quad * 4);
            u0 = __builtin_amdgcn_mfma_f32_16x16x32_bf16(a0, bw[kk], u0, 0, 0, 0);
            u1 = __builtin_amdgcn_mfma_f32_16x16x32_bf16(a1, bw[kk], u1, 0, 0, 0);
        }
        if (l16 < 4) {
#pragma unroll
            for (int r = 0; r < 4; ++r) {
                int ra = row0 + quad * 4 + r;
                int rb2 = ra + 16;
                if (ra < N) uall[(size_t)ra * 32 + k * 4 + l16] = u0[r];
                if (rb2 < N) uall[(size_t)rb2 * 32 + k * 4 + l16] = u1[r];
            }
        }
    }
}

// ---- aggregation 2 + softmax: v = dinv[i]*(sum us[j] + us[i]) + bias ----
// us[j] = dinv[j]*u[j]; so d*(sum + us[i]) = sum norm_e*u[j] + invdeg*u[i]
__global__ void __launch_bounds__(256) k_out(const unsigned* __restrict__ us,
        const int2* __restrict__ rpse, const int* __restrict__ csrc,
        const float* __restrict__ dinv, const float* __restrict__ bias2,
        float* __restrict__ out, int N) {
    int lane = threadIdx.x & 63;
    int wv = threadIdx.x >> 6;
    int i = blockIdx.x * 4 + wv;
    if (i >= N) return;
    int grp = lane >> 2, sub = lane & 3;
    const unsigned* usb = us + sub * 4;
    int2 se = rpse[i];
    int s = se.x, e = se.y;
    float2 a0[4] = {{0.f,0.f},{0.f,0.f},{0.f,0.f},{0.f,0.f}};
    float2 a1[4] = {{0.f,0.f},{0.f,0.f},{0.f,0.f},{0.f,0.f}};
    for (int base = s; base < e; base += 64) {
        int el = base + lane;
        int j_l = (el < e) ? csrc[el] : N;
        int cnt = e - base; if (cnt > 64) cnt = 64;
        for (int t = 0; t < cnt; t += 32) {
            int jj0 = __shfl(j_l, t + grp);
            int jj1 = __shfl(j_l, t + 16 + grp);
            const uint4 v0 = *(const uint4*)(usb + (size_t)jj0 * 16);
            const uint4 v1 = *(const uint4*)(usb + (size_t)jj1 * 16);
            acc8(a0, v0); acc8(a1, v1);
        }
    }
    float acc[8];
#pragma unroll
    for (int r = 0; r < 4; ++r) {
        acc[2 * r] = a0[r].x + a1[r].x;
        acc[2 * r + 1] = a0[r].y + a1[r].y;
    }
#pragma unroll
    for (int r = 0; r < 8; ++r) {
        acc[r] += __shfl_xor(acc[r], 4);
        acc[r] += __shfl_xor(acc[r], 8);
        acc[r] += __shfl_xor(acc[r], 16);
        acc[r] += __shfl_xor(acc[r], 32);
    }
    if (grp == 0) {
        const uint4 sv = *(const uint4*)(usb + (size_t)i * 16);
        float d = dinv[i];
        float4 bA = *(const float4*)(bias2 + sub * 8);
        float4 bB = *(const float4*)(bias2 + sub * 8 + 4);
        float w0 = d * (acc[0] + bflo(sv.x)) + bA.x;
        float w1 = d * (acc[1] + bfhi(sv.x)) + bA.y;
        float w2 = d * (acc[2] + bflo(sv.y)) + bA.z;
        float w4 = d * (acc[4] + bflo(sv.z)) + bB.x;
        float w5 = d * (acc[5] + bfhi(sv.z)) + bB.y;
        float w6 = d * (acc[6] + bflo(sv.w)) + bB.z;
        auto wr = [&](int b, float v0, float v1, float v2) {
            int ck = (b < 5) ? 3 : 2;
            float mx = fmaxf(v0, v1);
            if (ck == 3) mx = fmaxf(mx, v2);
            float e0 = __expf(v0 - mx), e1 = __expf(v1 - mx);
            float e2 = (ck == 3) ? __expf(v2 - mx) : 0.0f;
            float inv = 1.0f / (e0 + e1 + e2);
            size_t bb = (b < 5) ? (size_t)b * 3 * N + (size_t)i * 3
                                : (size_t)15 * N + (size_t)(b - 5) * 2 * N + (size_t)i * 2;
            out[bb] = e0 * inv;
            out[bb + 1] = e1 * inv;
            if (ck == 3) out[bb + 2] = e2 * inv;
        };
        wr(sub * 2, w0, w1, w2);
        if (sub < 3) wr(sub * 2 + 1, w4, w5, w6);
    }
}

// ---- launch -------------------------------------------------------------
extern "C" void kernel_launch(void* const* d_in, const int* in_sizes, int n_in,
                              void* d_out, int out_size, void* d_ws, size_t ws_size,
                              hipStream_t stream) {
    (void)n_in; (void)out_size; (void)ws_size;
    const float* x   = (const float*)d_in[0];
    const int*   ei  = (const int*)d_in[1];
    const float* gw  = (const float*)d_in[2];
    const float* gb  = (const float*)d_in[3];
    const float* r3w = (const float*)d_in[4];
    const float* r3b = (const float*)d_in[5];
    const float* r2w = (const float*)d_in[6];
    const float* r2b = (const float*)d_in[7];
    float* out = (float*)d_out;
    int N = in_sizes[0] / H;   // 100000
    int E = in_sizes[1] / 2;   // 1600000
    int NB = (N + 255) >> 8;   // 391 buckets

    char* p = (char*)d_ws;
    auto alloc = [&](size_t bytes) {
        char* q = p;
        p += (bytes + 255) & ~(size_t)255;
        return q;
    };
    unsigned*       xs     = (unsigned*)alloc((size_t)(N + 1) * 64 * 4);  // scaled x bf16 + zero row
    unsigned*       pxb    = (unsigned*)alloc((size_t)N * 64 * 4);
    unsigned short* Wt     = (unsigned short*)alloc((size_t)7 * 16384 * 2);
    unsigned short* WRb    = (unsigned short*)alloc((size_t)14336 * 2);
    float*          bias2  = (float*)alloc(32 * 4);
    int*            gcur   = (int*)alloc(512 * 4);
    int*            tmp_e  = (int*)alloc((size_t)NB * CAP * 4);
    int2*           rpse   = (int2*)alloc((size_t)N * 8);
    float*          dinv   = (float*)alloc((size_t)N * 4);
    int*            csrc   = (int*)alloc((size_t)NB * CAP * 4);
    float*          uall   = (float*)alloc((size_t)N * 32 * 4);           // fp32 (unscaled)
    unsigned*       usb    = (unsigned*)alloc((size_t)(N + 1) * 16 * 4);  // bf16 dinv-scaled + zero row

    hipMemsetAsync(gcur, 0, 512 * 4, stream);
    k_scatter<<<256, 256, 0, stream>>>(ei, gcur, tmp_e, E);
    k_csrAB<<<NB, 256, 0, stream>>>(tmp_e, gcur, rpse, dinv, csrc, N);
    int prep_threads = N * 64 + 64 + 114688 + 14368;
    k_prep<<<(prep_threads + 255) / 256, 256, 0, stream>>>(x, dinv, xs, N,
            gw, gb, r3w, r3b, r2w, r2b, Wt, WRb, bias2);
    k_px<<<(N + 3) / 4, 256, 0, stream>>>(xs, rpse, csrc, dinv, pxb, N);
    dim3 gg((N + 511) / 512, 7);
    k_gemm<<<gg, 256, 0, stream>>>((const unsigned short*)pxb, Wt, gb, WRb, uall, N);
    k_uscale<<<(N * 16 + 16 + 255) / 256, 256, 0, stream>>>(uall, dinv, usb, N);
    k_out<<<(N + 3) / 4, 256, 0, stream>>>(usb, rpse, csrc, dinv, bias2, out, N);
}

// Round 14
// 299.926 us; speedup vs baseline: 1.3656x; 1.0108x over previous
//
#include <hip/hip_runtime.h>

#define H 128
#define CAP 8192   // per-bucket capacity; mean fill ~4096, sigma ~64

typedef __attribute__((ext_vector_type(8))) short bf16x8;
typedef __attribute__((ext_vector_type(4))) float f32x4;

__device__ __forceinline__ unsigned short f2bf(float f) {
    unsigned u = __float_as_uint(f);
    u += 0x7FFFu + ((u >> 16) & 1u);
    return (unsigned short)(u >> 16);
}
__device__ __forceinline__ float bflo(unsigned v) { return __uint_as_float(v << 16); }
__device__ __forceinline__ float bfhi(unsigned v) { return __uint_as_float(v & 0xFFFF0000u); }

// ---- scatter edges into fixed-capacity dst-buckets ----------------------
__global__ void __launch_bounds__(256) k_scatter(const int* __restrict__ ei,
        int* __restrict__ gcur, int* __restrict__ tmp_e, int E) {
    __shared__ int hist[512], base[512], fill[512];
    int blk = blockIdx.x, t = threadIdx.x;
    int chunk = (E + gridDim.x - 1) / gridDim.x;
    int c0 = blk * chunk;
    int c1 = c0 + chunk; if (c1 > E) c1 = E;
    hist[t] = 0; hist[t + 256] = 0;
    __syncthreads();
    for (int e = c0 + t; e < c1; e += 256)
        atomicAdd(&hist[ei[E + e] >> 8], 1);
    __syncthreads();
    for (int u = t; u < 512; u += 256) {
        int h = hist[u];
        base[u] = h ? atomicAdd(&gcur[u], h) : 0;
        fill[u] = 0;
    }
    __syncthreads();
    for (int e = c0 + t; e < c1; e += 256) {
        int d = ei[E + e], s = ei[e];
        int bb = d >> 8;
        int p = base[bb] + atomicAdd(&fill[bb], 1);
        if (p < CAP) tmp_e[bb * CAP + p] = s | ((d & 255) << 24);
    }
}

// merged per-bucket: count + scan -> rpse {start,end}, dinv; scatter csrc
__global__ void __launch_bounds__(256) k_csrAB(const int* __restrict__ tmp_e,
        const int* __restrict__ gcur, int2* __restrict__ rpse,
        float* __restrict__ dinv, int* __restrict__ csrc, int N) {
    __shared__ int cnt[256];
    __shared__ int sh[256];
    __shared__ int fill[256];
    int b = blockIdx.x, t = threadIdx.x;
    int e0 = b * CAP;
    int tot = gcur[b]; if (tot > CAP) tot = CAP;
    int e1 = e0 + tot;
    cnt[t] = 0;
    __syncthreads();
    for (int e = e0 + t; e < e1; e += 256)
        atomicAdd(&cnt[(unsigned)tmp_e[e] >> 24], 1);
    __syncthreads();
    int v = cnt[t];
    sh[t] = v;
    __syncthreads();
    for (int off = 1; off < 256; off <<= 1) {
        int u = (t >= off) ? sh[t - off] : 0;
        __syncthreads();
        sh[t] += u;
        __syncthreads();
    }
    int mystart = e0 + sh[t] - v;
    fill[t] = mystart;
    int gid = (b << 8) + t;
    if (gid < N) {
        rpse[gid] = make_int2(mystart, mystart + v);
        dinv[gid] = rsqrtf((float)(v + 1));
    }
    __syncthreads();
    for (int e = e0 + t; e < e1; e += 256) {
        int te = tmp_e[e];
        int l = (unsigned)te >> 24;
        int p = atomicAdd(&fill[l], 1);
        csrc[p] = te & 0xFFFFFF;
    }
}

// ---- merged prep: xs scale (+zero row) AND weight prep ------------------
__global__ void k_prep(const float* __restrict__ x, const float* __restrict__ dinv,
                       unsigned* __restrict__ xs, int N,
                       const float* __restrict__ W, const float* __restrict__ b,
                       const float* __restrict__ r3w, const float* __restrict__ r3b,
                       const float* __restrict__ r2w, const float* __restrict__ r2b,
                       unsigned short* __restrict__ Wt, unsigned short* __restrict__ WRb,
                       float* __restrict__ bias2) {
    int gi = blockIdx.x * blockDim.x + threadIdx.x;
    int total = N * 64;
    if (gi < total) {
        float d = dinv[gi >> 6];
        float2 v = ((const float2*)x)[gi];
        xs[gi] = (unsigned)f2bf(d * v.x) | ((unsigned)f2bf(d * v.y) << 16);
        return;
    }
    if (gi < total + 64) { xs[gi] = 0; return; }
    int idx = gi - (total + 64);
    if (idx < 114688) {
        int k = idx >> 14;
        int f = (idx >> 7) & 127;
        int h = idx & 127;
        Wt[(k << 14) + (h << 7) + f] = f2bf(W[idx]);
        return;
    }
    int idx2 = idx - 114688;
    if (idx2 < 14336) {
        int j = idx2 & 7;
        int lane = (idx2 >> 3) & 63;
        int kk = (idx2 >> 9) & 3;
        int k = idx2 >> 11;
        int c = lane & 15;
        int off = ((lane >> 4) << 3) + j;
        int f = kk * 32 + (off >> 1) + ((off & 1) << 4);
        int ck = (k < 5) ? 3 : 2;
        float s = 0.0f;
        if (c < ck) {
            const float* R = (k < 5) ? (r3w + (size_t)(k * 3 + c) * H)
                                     : (r2w + (size_t)((k - 5) * 2 + c) * H);
            const float* Wk = W + (k << 14) + (f << 7);
            for (int h = 0; h < H; ++h) s += Wk[h] * R[h];
        }
        WRb[idx2] = f2bf(s);
    } else if (idx2 < 14336 + 32) {
        int c32 = idx2 - 14336;
        int k = c32 >> 2, c = c32 & 3;
        int ck = (k < 5) ? 3 : 2;
        float t = 0.0f;
        if (c < ck) {
            const float* R = (k < 5) ? (r3w + (size_t)(k * 3 + c) * H)
                                     : (r2w + (size_t)((k - 5) * 2 + c) * H);
            const float* bk = b + k * H;
            for (int h = 0; h < H; ++h) t += bk[h] * R[h];
            t += (k < 5) ? r3b[k * 3 + c] : r2b[(k - 5) * 2 + c];
        }
        bias2[c32] = t;
    }
}

// ---- prep: us[j] = bf16(dinv[j] * u[j]); zero row at index N ------------
__global__ void k_uscale(const float* __restrict__ u, const float* __restrict__ dinv,
                         unsigned* __restrict__ us, int N) {
    int i = blockIdx.x * blockDim.x + threadIdx.x;
    int total = N * 16;
    if (i < total) {
        float d = dinv[i >> 4];
        float2 v = ((const float2*)u)[i];
        us[i] = (unsigned)f2bf(d * v.x) | ((unsigned)f2bf(d * v.y) << 16);
    } else if (i < total + 16) {
        us[i] = 0;
    }
}

__device__ __forceinline__ void acc8(float2* a, const uint4 v) {
    a[0].x += bflo(v.x); a[0].y += bfhi(v.x);
    a[1].x += bflo(v.y); a[1].y += bfhi(v.y);
    a[2].x += bflo(v.z); a[2].y += bfhi(v.z);
    a[3].x += bflo(v.w); a[3].y += bfhi(v.w);
}

// ---- aggregation 1: px[i] = dinv[i] * (sum_j xs[j] + xs[i]) -------------
__global__ void __launch_bounds__(256) k_px(const unsigned* __restrict__ xs,
        const int2* __restrict__ rpse, const int* __restrict__ csrc,
        const float* __restrict__ dinv, unsigned* __restrict__ pxb, int N) {
    int lane = threadIdx.x & 63;
    int wv = threadIdx.x >> 6;
    int i = blockIdx.x * 4 + wv;
    if (i >= N) return;
    int grp = lane >> 4, sub = lane & 15;
    const unsigned* xbs = xs + sub * 4;
    int2 se = rpse[i];
    int s = se.x, e = se.y;
    float2 a0[4] = {{0.f,0.f},{0.f,0.f},{0.f,0.f},{0.f,0.f}};
    float2 a1[4] = {{0.f,0.f},{0.f,0.f},{0.f,0.f},{0.f,0.f}};
    for (int base = s; base < e; base += 64) {
        int el = base + lane;
        int j_l = (el < e) ? csrc[el] : N;
        int cnt = e - base; if (cnt > 64) cnt = 64;
        for (int t = 0; t < cnt; t += 16) {
            int jj0 = __shfl(j_l, t + grp);
            int jj1 = __shfl(j_l, t + 4 + grp);
            int jj2 = __shfl(j_l, t + 8 + grp);
            int jj3 = __shfl(j_l, t + 12 + grp);
            const uint4 v0 = *(const uint4*)(xbs + (size_t)jj0 * 64);
            const uint4 v1 = *(const uint4*)(xbs + (size_t)jj1 * 64);
            const uint4 v2 = *(const uint4*)(xbs + (size_t)jj2 * 64);
            const uint4 v3 = *(const uint4*)(xbs + (size_t)jj3 * 64);
            acc8(a0, v0); acc8(a1, v1); acc8(a0, v2); acc8(a1, v3);
        }
    }
    float acc[8];
#pragma unroll
    for (int r = 0; r < 4; ++r) {
        acc[2 * r] = a0[r].x + a1[r].x;
        acc[2 * r + 1] = a0[r].y + a1[r].y;
    }
#pragma unroll
    for (int r = 0; r < 8; ++r) {
        acc[r] += __shfl_xor(acc[r], 16);
        acc[r] += __shfl_xor(acc[r], 32);
    }
    if (grp == 0) {
        const uint4 v = *(const uint4*)(xbs + (size_t)i * 64);
        float d = dinv[i];
        uint4 o;
        o.x = (unsigned)f2bf(d * (acc[0] + bflo(v.x))) | ((unsigned)f2bf(d * (acc[1] + bfhi(v.x))) << 16);
        o.y = (unsigned)f2bf(d * (acc[2] + bflo(v.y))) | ((unsigned)f2bf(d * (acc[3] + bfhi(v.y))) << 16);
        o.z = (unsigned)f2bf(d * (acc[4] + bflo(v.z))) | ((unsigned)f2bf(d * (acc[5] + bfhi(v.z))) << 16);
        o.w = (unsigned)f2bf(d * (acc[6] + bflo(v.w))) | ((unsigned)f2bf(d * (acc[7] + bfhi(v.w))) << 16);
        *(uint4*)(pxb + (size_t)i * 64 + sub * 4) = o;
    }
}

// ---- GEMM: uall = (relu(px@Wk + bk)) @ WR_k -----------------------------
// Store-only epilogue (R7/R12 rule: nothing else in the epilogue).
// Projection accumulated PER COL-GROUP -> h1 buffer is 640 words/wave,
// LDS 45056 B total -> 3 blocks/CU (was 2 at 75776).
__global__ void __launch_bounds__(256, 3) k_gemm(const unsigned short* __restrict__ pxb,
        const unsigned short* __restrict__ Wt, const float* __restrict__ gb,
        const unsigned short* __restrict__ WRb, float* __restrict__ uall, int N) {
    __shared__ __align__(16) unsigned short Bs[128 * 136];
    __shared__ __align__(16) unsigned h1w[4][640];   // 32 regions x 20 words per wave
    int k = blockIdx.y;
    int wv = threadIdx.x >> 6;
    int lane = threadIdx.x & 63;
    int quad = lane >> 4, l16 = lane & 15;

    {
        const unsigned short* src = Wt + (k << 14);
        int t = threadIdx.x;
#pragma unroll
        for (int i = 0; i < 8; ++i) {
            int li = i * 256 + t;
            int f = li >> 4, seg = li & 15;
            *(bf16x8*)(Bs + f * 136 + seg * 8) = *(const bf16x8*)(src + f * 128 + seg * 8);
        }
    }
    __syncthreads();

    unsigned* wl = &h1w[wv][0];
    int rowbase = blockIdx.x * 512 + wv * 32;

    bf16x8 af[2][2][4];
    {
        int rb0 = rowbase;
#pragma unroll
        for (int rb = 0; rb < 2; ++rb) {
            int r = rb0 + rb * 16 + l16;
            if (r >= N) r = N - 1;
#pragma unroll
            for (int kk = 0; kk < 4; ++kk)
                af[0][rb][kk] = *(const bf16x8*)(pxb + (size_t)r * H + kk * 32 + quad * 8);
        }
    }

    float bi[4][2];
#pragma unroll
    for (int p = 0; p < 4; ++p) {
        bi[p][0] = gb[k * H + 32 * p + l16];
        bi[p][1] = gb[k * H + 32 * p + 16 + l16];
    }
    bf16x8 bw[4];
#pragma unroll
    for (int kk = 0; kk < 4; ++kk)
        bw[kk] = *(const bf16x8*)(WRb + (size_t)((k * 4 + kk) * 64 + lane) * 8);

    for (int t = 0; t < 4; ++t) {
        if (t < 3) {
            int rb0 = rowbase + (t + 1) * 128;
#pragma unroll
            for (int rb = 0; rb < 2; ++rb) {
                int r = rb0 + rb * 16 + l16;
                if (r >= N) r = N - 1;
#pragma unroll
                for (int kk = 0; kk < 4; ++kk)
                    af[(t + 1) & 1][rb][kk] = *(const bf16x8*)(pxb + (size_t)r * H + kk * 32 + quad * 8);
            }
        }
        int row0 = rowbase + t * 128;
        f32x4 u0 = {}, u1 = {};
#pragma unroll
        for (int p = 0; p < 4; ++p) {
            f32x4 cacc[2][2] = {};
#pragma unroll
            for (int kk = 0; kk < 4; ++kk) {
                bf16x8 b0 = *(const bf16x8*)(Bs + (32 * p + l16) * 136 + kk * 32 + quad * 8);
                bf16x8 b1 = *(const bf16x8*)(Bs + (32 * p + 16 + l16) * 136 + kk * 32 + quad * 8);
#pragma unroll
                for (int rb = 0; rb < 2; ++rb) {
                    cacc[rb][0] = __builtin_amdgcn_mfma_f32_16x16x32_bf16(af[t & 1][rb][kk], b0, cacc[rb][0], 0, 0, 0);
                    cacc[rb][1] = __builtin_amdgcn_mfma_f32_16x16x32_bf16(af[t & 1][rb][kk], b1, cacc[rb][1], 0, 0, 0);
                }
            }
            // transpose this col-group through wave-private LDS (in-order DS
            // per wave makes the write->read->overwrite sequence safe)
#pragma unroll
            for (int rb = 0; rb < 2; ++rb)
#pragma unroll
                for (int r = 0; r < 4; ++r) {
                    float lo = fmaxf(cacc[rb][0][r] + bi[p][0], 0.0f);
                    float hi = fmaxf(cacc[rb][1][r] + bi[p][1], 0.0f);
                    unsigned pk = (unsigned)f2bf(lo) | ((unsigned)f2bf(hi) << 16);
                    wl[(rb * 16 + quad * 4 + r) * 20 + l16] = pk;
                }
            bf16x8 a0 = *(const bf16x8*)(wl + l16 * 20 + quad * 4);
            bf16x8 a1 = *(const bf16x8*)(wl + (16 + l16) * 20 + quad * 4);
            u0 = __builtin_amdgcn_mfma_f32_16x16x32_bf16(a0, bw[p], u0, 0, 0, 0);
            u1 = __builtin_amdgcn_mfma_f32_16x16x32_bf16(a1, bw[p], u1, 0, 0, 0);
        }
        if (l16 < 4) {
#pragma unroll
            for (int r = 0; r < 4; ++r) {
                int ra = row0 + quad * 4 + r;
                int rb2 = ra + 16;
                if (ra < N) uall[(size_t)ra * 32 + k * 4 + l16] = u0[r];
                if (rb2 < N) uall[(size_t)rb2 * 32 + k * 4 + l16] = u1[r];
            }
        }
    }
}

// ---- aggregation 2 + softmax: v = dinv[i]*(sum us[j] + us[i]) + bias ----
__global__ void __launch_bounds__(256) k_out(const unsigned* __restrict__ us,
        const int2* __restrict__ rpse, const int* __restrict__ csrc,
        const float* __restrict__ dinv, const float* __restrict__ bias2,
        float* __restrict__ out, int N) {
    int lane = threadIdx.x & 63;
    int wv = threadIdx.x >> 6;
    int i = blockIdx.x * 4 + wv;
    if (i >= N) return;
    int grp = lane >> 2, sub = lane & 3;
    const unsigned* usb = us + sub * 4;
    int2 se = rpse[i];
    int s = se.x, e = se.y;
    float2 a0[4] = {{0.f,0.f},{0.f,0.f},{0.f,0.f},{0.f,0.f}};
    float2 a1[4] = {{0.f,0.f},{0.f,0.f},{0.f,0.f},{0.f,0.f}};
    for (int base = s; base < e; base += 64) {
        int el = base + lane;
        int j_l = (el < e) ? csrc[el] : N;
        int cnt = e - base; if (cnt > 64) cnt = 64;
        for (int t = 0; t < cnt; t += 32) {
            int jj0 = __shfl(j_l, t + grp);
            int jj1 = __shfl(j_l, t + 16 + grp);
            const uint4 v0 = *(const uint4*)(usb + (size_t)jj0 * 16);
            const uint4 v1 = *(const uint4*)(usb + (size_t)jj1 * 16);
            acc8(a0, v0); acc8(a1, v1);
        }
    }
    float acc[8];
#pragma unroll
    for (int r = 0; r < 4; ++r) {
        acc[2 * r] = a0[r].x + a1[r].x;
        acc[2 * r + 1] = a0[r].y + a1[r].y;
    }
#pragma unroll
    for (int r = 0; r < 8; ++r) {
        acc[r] += __shfl_xor(acc[r], 4);
        acc[r] += __shfl_xor(acc[r], 8);
        acc[r] += __shfl_xor(acc[r], 16);
        acc[r] += __shfl_xor(acc[r], 32);
    }
    if (grp == 0) {
        const uint4 sv = *(const uint4*)(usb + (size_t)i * 16);
        float d = dinv[i];
        float4 bA = *(const float4*)(bias2 + sub * 8);
        float4 bB = *(const float4*)(bias2 + sub * 8 + 4);
        float w0 = d * (acc[0] + bflo(sv.x)) + bA.x;
        float w1 = d * (acc[1] + bfhi(sv.x)) + bA.y;
        float w2 = d * (acc[2] + bflo(sv.y)) + bA.z;
        float w4 = d * (acc[4] + bflo(sv.z)) + bB.x;
        float w5 = d * (acc[5] + bfhi(sv.z)) + bB.y;
        float w6 = d * (acc[6] + bflo(sv.w)) + bB.z;
        auto wr = [&](int b, float v0, float v1, float v2) {
            int ck = (b < 5) ? 3 : 2;
            float mx = fmaxf(v0, v1);
            if (ck == 3) mx = fmaxf(mx, v2);
            float e0 = __expf(v0 - mx), e1 = __expf(v1 - mx);
            float e2 = (ck == 3) ? __expf(v2 - mx) : 0.0f;
            float inv = 1.0f / (e0 + e1 + e2);
            size_t bb = (b < 5) ? (size_t)b * 3 * N + (size_t)i * 3
                                : (size_t)15 * N + (size_t)(b - 5) * 2 * N + (size_t)i * 2;
            out[bb] = e0 * inv;
            out[bb + 1] = e1 * inv;
            if (ck == 3) out[bb + 2] = e2 * inv;
        };
        wr(sub * 2, w0, w1, w2);
        if (sub < 3) wr(sub * 2 + 1, w4, w5, w6);
    }
}

// ---- launch -------------------------------------------------------------
extern "C" void kernel_launch(void* const* d_in, const int* in_sizes, int n_in,
                              void* d_out, int out_size, void* d_ws, size_t ws_size,
                              hipStream_t stream) {
    (void)n_in; (void)out_size; (void)ws_size;
    const float* x   = (const float*)d_in[0];
    const int*   ei  = (const int*)d_in[1];
    const float* gw  = (const float*)d_in[2];
    const float* gb  = (const float*)d_in[3];
    const float* r3w = (const float*)d_in[4];
    const float* r3b = (const float*)d_in[5];
    const float* r2w = (const float*)d_in[6];
    const float* r2b = (const float*)d_in[7];
    float* out = (float*)d_out;
    int N = in_sizes[0] / H;   // 100000
    int E = in_sizes[1] / 2;   // 1600000
    int NB = (N + 255) >> 8;   // 391 buckets

    char* p = (char*)d_ws;
    auto alloc = [&](size_t bytes) {
        char* q = p;
        p += (bytes + 255) & ~(size_t)255;
        return q;
    };
    unsigned*       xs     = (unsigned*)alloc((size_t)(N + 1) * 64 * 4);
    unsigned*       pxb    = (unsigned*)alloc((size_t)N * 64 * 4);
    unsigned short* Wt     = (unsigned short*)alloc((size_t)7 * 16384 * 2);
    unsigned short* WRb    = (unsigned short*)alloc((size_t)14336 * 2);
    float*          bias2  = (float*)alloc(32 * 4);
    int*            gcur   = (int*)alloc(512 * 4);
    int*            tmp_e  = (int*)alloc((size_t)NB * CAP * 4);
    int2*           rpse   = (int2*)alloc((size_t)N * 8);
    float*          dinv   = (float*)alloc((size_t)N * 4);
    int*            csrc   = (int*)alloc((size_t)NB * CAP * 4);
    float*          uall   = (float*)alloc((size_t)N * 32 * 4);
    unsigned*       usb    = (unsigned*)alloc((size_t)(N + 1) * 16 * 4);

    hipMemsetAsync(gcur, 0, 512 * 4, stream);
    k_scatter<<<256, 256, 0, stream>>>(ei, gcur, tmp_e, E);
    k_csrAB<<<NB, 256, 0, stream>>>(tmp_e, gcur, rpse, dinv, csrc, N);
    int prep_threads = N * 64 + 64 + 114688 + 14368;
    k_prep<<<(prep_threads + 255) / 256, 256, 0, stream>>>(x, dinv, xs, N,
            gw, gb, r3w, r3b, r2w, r2b, Wt, WRb, bias2);
    k_px<<<(N + 3) / 4, 256, 0, stream>>>(xs, rpse, csrc, dinv, pxb, N);
    dim3 gg((N + 511) / 512, 7);
    k_gemm<<<gg, 256, 0, stream>>>((const unsigned short*)pxb, Wt, gb, WRb, uall, N);
    k_uscale<<<(N * 16 + 16 + 255) / 256, 256, 0, stream>>>(uall, dinv, usb, N);
    k_out<<<(N + 3) / 4, 256, 0, stream>>>(usb, rpse, csrc, dinv, bias2, out, N);
}

// Round 15
// 297.381 us; speedup vs baseline: 1.3773x; 1.0086x over previous
//
#include <hip/hip_runtime.h>

#define H 128
#define CAP 8192   // per-bucket capacity; mean fill ~4096, sigma ~64

typedef __attribute__((ext_vector_type(8))) short bf16x8;
typedef __attribute__((ext_vector_type(4))) float f32x4;

__device__ __forceinline__ unsigned short f2bf(float f) {
    unsigned u = __float_as_uint(f);
    u += 0x7FFFu + ((u >> 16) & 1u);
    return (unsigned short)(u >> 16);
}
__device__ __forceinline__ float bflo(unsigned v) { return __uint_as_float(v << 16); }
__device__ __forceinline__ float bfhi(unsigned v) { return __uint_as_float(v & 0xFFFF0000u); }

// ---- scatter edges into fixed-capacity dst-buckets ----------------------
// 512 blocks (2/CU) for latency overlap between hist and scatter phases
__global__ void __launch_bounds__(256) k_scatter(const int* __restrict__ ei,
        int* __restrict__ gcur, int* __restrict__ tmp_e, int E) {
    __shared__ int hist[512], base[512], fill[512];
    int blk = blockIdx.x, t = threadIdx.x;
    int chunk = (E + gridDim.x - 1) / gridDim.x;
    int c0 = blk * chunk;
    int c1 = c0 + chunk; if (c1 > E) c1 = E;
    hist[t] = 0; hist[t + 256] = 0;
    __syncthreads();
    for (int e = c0 + t; e < c1; e += 256)
        atomicAdd(&hist[ei[E + e] >> 8], 1);
    __syncthreads();
    for (int u = t; u < 512; u += 256) {
        int h = hist[u];
        base[u] = h ? atomicAdd(&gcur[u], h) : 0;
        fill[u] = 0;
    }
    __syncthreads();
    for (int e = c0 + t; e < c1; e += 256) {
        int d = ei[E + e], s = ei[e];
        int bb = d >> 8;
        int p = base[bb] + atomicAdd(&fill[bb], 1);
        if (p < CAP) tmp_e[bb * CAP + p] = s | ((d & 255) << 24);
    }
}

// merged per-bucket: count + scan -> rpse {start,end}, dinv; scatter csrc
// 512 threads: edge sweeps in half the iterations; scan zero-padded to 512
__global__ void __launch_bounds__(512) k_csrAB(const int* __restrict__ tmp_e,
        const int* __restrict__ gcur, int2* __restrict__ rpse,
        float* __restrict__ dinv, int* __restrict__ csrc, int N) {
    __shared__ int cnt[256];
    __shared__ int sh[512];
    __shared__ int fill[256];
    int b = blockIdx.x, t = threadIdx.x;
    int e0 = b * CAP;
    int tot = gcur[b]; if (tot > CAP) tot = CAP;
    int e1 = e0 + tot;
    if (t < 256) cnt[t] = 0;
    __syncthreads();
    for (int e = e0 + t; e < e1; e += 512)
        atomicAdd(&cnt[(unsigned)tmp_e[e] >> 24], 1);
    __syncthreads();
    int v = (t < 256) ? cnt[t] : 0;
    sh[t] = v;
    __syncthreads();
    for (int off = 1; off < 256; off <<= 1) {
        int u = (t >= off) ? sh[t - off] : 0;
        __syncthreads();
        sh[t] += u;
        __syncthreads();
    }
    if (t < 256) {
        int mystart = e0 + sh[t] - v;
        fill[t] = mystart;
        int gid = (b << 8) + t;
        if (gid < N) {
            rpse[gid] = make_int2(mystart, mystart + v);
            dinv[gid] = rsqrtf((float)(v + 1));
        }
    }
    __syncthreads();
    for (int e = e0 + t; e < e1; e += 512) {
        int te = tmp_e[e];
        int l = (unsigned)te >> 24;
        int p = atomicAdd(&fill[l], 1);
        csrc[p] = te & 0xFFFFFF;
    }
}

// ---- merged prep: xs scale (+zero row) AND weight prep ------------------
__global__ void k_prep(const float* __restrict__ x, const float* __restrict__ dinv,
                       unsigned* __restrict__ xs, int N,
                       const float* __restrict__ W, const float* __restrict__ b,
                       const float* __restrict__ r3w, const float* __restrict__ r3b,
                       const float* __restrict__ r2w, const float* __restrict__ r2b,
                       unsigned short* __restrict__ Wt, unsigned short* __restrict__ WRb,
                       float* __restrict__ bias2) {
    int gi = blockIdx.x * blockDim.x + threadIdx.x;
    int total = N * 64;
    if (gi < total) {
        float d = dinv[gi >> 6];
        float2 v = ((const float2*)x)[gi];
        xs[gi] = (unsigned)f2bf(d * v.x) | ((unsigned)f2bf(d * v.y) << 16);
        return;
    }
    if (gi < total + 64) { xs[gi] = 0; return; }
    int idx = gi - (total + 64);
    if (idx < 114688) {
        int k = idx >> 14;
        int f = (idx >> 7) & 127;
        int h = idx & 127;
        Wt[(k << 14) + (h << 7) + f] = f2bf(W[idx]);
        return;
    }
    int idx2 = idx - 114688;
    if (idx2 < 14336) {
        int j = idx2 & 7;
        int lane = (idx2 >> 3) & 63;
        int kk = (idx2 >> 9) & 3;
        int k = idx2 >> 11;
        int c = lane & 15;
        int off = ((lane >> 4) << 3) + j;
        int f = kk * 32 + (off >> 1) + ((off & 1) << 4);
        int ck = (k < 5) ? 3 : 2;
        float s = 0.0f;
        if (c < ck) {
            const float* R = (k < 5) ? (r3w + (size_t)(k * 3 + c) * H)
                                     : (r2w + (size_t)((k - 5) * 2 + c) * H);
            const float* Wk = W + (k << 14) + (f << 7);
            for (int h = 0; h < H; ++h) s += Wk[h] * R[h];
        }
        WRb[idx2] = f2bf(s);
    } else if (idx2 < 14336 + 32) {
        int c32 = idx2 - 14336;
        int k = c32 >> 2, c = c32 & 3;
        int ck = (k < 5) ? 3 : 2;
        float t = 0.0f;
        if (c < ck) {
            const float* R = (k < 5) ? (r3w + (size_t)(k * 3 + c) * H)
                                     : (r2w + (size_t)((k - 5) * 2 + c) * H);
            const float* bk = b + k * H;
            for (int h = 0; h < H; ++h) t += bk[h] * R[h];
            t += (k < 5) ? r3b[k * 3 + c] : r2b[(k - 5) * 2 + c];
        }
        bias2[c32] = t;
    }
}

// ---- prep: us[j] = bf16(dinv[j] * u[j]); zero row at index N ------------
__global__ void k_uscale(const float* __restrict__ u, const float* __restrict__ dinv,
                         unsigned* __restrict__ us, int N) {
    int i = blockIdx.x * blockDim.x + threadIdx.x;
    int total = N * 16;
    if (i < total) {
        float d = dinv[i >> 4];
        float2 v = ((const float2*)u)[i];
        us[i] = (unsigned)f2bf(d * v.x) | ((unsigned)f2bf(d * v.y) << 16);
    } else if (i < total + 16) {
        us[i] = 0;
    }
}

__device__ __forceinline__ void acc8(float2* a, const uint4 v) {
    a[0].x += bflo(v.x); a[0].y += bfhi(v.x);
    a[1].x += bflo(v.y); a[1].y += bfhi(v.y);
    a[2].x += bflo(v.z); a[2].y += bfhi(v.z);
    a[3].x += bflo(v.w); a[3].y += bfhi(v.w);
}

// ---- aggregation 1: px[i] = dinv[i] * (sum_j xs[j] + xs[i]) -------------
__global__ void __launch_bounds__(256) k_px(const unsigned* __restrict__ xs,
        const int2* __restrict__ rpse, const int* __restrict__ csrc,
        const float* __restrict__ dinv, unsigned* __restrict__ pxb, int N) {
    int lane = threadIdx.x & 63;
    int wv = threadIdx.x >> 6;
    int i = blockIdx.x * 4 + wv;
    if (i >= N) return;
    int grp = lane >> 4, sub = lane & 15;
    const unsigned* xbs = xs + sub * 4;
    int2 se = rpse[i];
    int s = se.x, e = se.y;
    float2 a0[4] = {{0.f,0.f},{0.f,0.f},{0.f,0.f},{0.f,0.f}};
    float2 a1[4] = {{0.f,0.f},{0.f,0.f},{0.f,0.f},{0.f,0.f}};
    for (int base = s; base < e; base += 64) {
        int el = base + lane;
        int j_l = (el < e) ? csrc[el] : N;
        int cnt = e - base; if (cnt > 64) cnt = 64;
        for (int t = 0; t < cnt; t += 16) {
            int jj0 = __shfl(j_l, t + grp);
            int jj1 = __shfl(j_l, t + 4 + grp);
            int jj2 = __shfl(j_l, t + 8 + grp);
            int jj3 = __shfl(j_l, t + 12 + grp);
            const uint4 v0 = *(const uint4*)(xbs + (size_t)jj0 * 64);
            const uint4 v1 = *(const uint4*)(xbs + (size_t)jj1 * 64);
            const uint4 v2 = *(const uint4*)(xbs + (size_t)jj2 * 64);
            const uint4 v3 = *(const uint4*)(xbs + (size_t)jj3 * 64);
            acc8(a0, v0); acc8(a1, v1); acc8(a0, v2); acc8(a1, v3);
        }
    }
    float acc[8];
#pragma unroll
    for (int r = 0; r < 4; ++r) {
        acc[2 * r] = a0[r].x + a1[r].x;
        acc[2 * r + 1] = a0[r].y + a1[r].y;
    }
#pragma unroll
    for (int r = 0; r < 8; ++r) {
        acc[r] += __shfl_xor(acc[r], 16);
        acc[r] += __shfl_xor(acc[r], 32);
    }
    if (grp == 0) {
        const uint4 v = *(const uint4*)(xbs + (size_t)i * 64);
        float d = dinv[i];
        uint4 o;
        o.x = (unsigned)f2bf(d * (acc[0] + bflo(v.x))) | ((unsigned)f2bf(d * (acc[1] + bfhi(v.x))) << 16);
        o.y = (unsigned)f2bf(d * (acc[2] + bflo(v.y))) | ((unsigned)f2bf(d * (acc[3] + bfhi(v.y))) << 16);
        o.z = (unsigned)f2bf(d * (acc[4] + bflo(v.z))) | ((unsigned)f2bf(d * (acc[5] + bfhi(v.z))) << 16);
        o.w = (unsigned)f2bf(d * (acc[6] + bflo(v.w))) | ((unsigned)f2bf(d * (acc[7] + bfhi(v.w))) << 16);
        *(uint4*)(pxb + (size_t)i * 64 + sub * 4) = o;
    }
}

// ---- GEMM: uall = (relu(px@Wk + bk)) @ WR_k -----------------------------
// Store-only epilogue (R7/R12 rule). Per-col-group projection keeps h1w at
// 640 words/wave -> LDS 45056 B -> 3 blocks/CU.
__global__ void __launch_bounds__(256, 3) k_gemm(const unsigned short* __restrict__ pxb,
        const unsigned short* __restrict__ Wt, const float* __restrict__ gb,
        const unsigned short* __restrict__ WRb, float* __restrict__ uall, int N) {
    __shared__ __align__(16) unsigned short Bs[128 * 136];
    __shared__ __align__(16) unsigned h1w[4][640];
    int k = blockIdx.y;
    int wv = threadIdx.x >> 6;
    int lane = threadIdx.x & 63;
    int quad = lane >> 4, l16 = lane & 15;

    {
        const unsigned short* src = Wt + (k << 14);
        int t = threadIdx.x;
#pragma unroll
        for (int i = 0; i < 8; ++i) {
            int li = i * 256 + t;
            int f = li >> 4, seg = li & 15;
            *(bf16x8*)(Bs + f * 136 + seg * 8) = *(const bf16x8*)(src + f * 128 + seg * 8);
        }
    }
    __syncthreads();

    unsigned* wl = &h1w[wv][0];
    int rowbase = blockIdx.x * 512 + wv * 32;

    bf16x8 af[2][2][4];
    {
        int rb0 = rowbase;
#pragma unroll
        for (int rb = 0; rb < 2; ++rb) {
            int r = rb0 + rb * 16 + l16;
            if (r >= N) r = N - 1;
#pragma unroll
            for (int kk = 0; kk < 4; ++kk)
                af[0][rb][kk] = *(const bf16x8*)(pxb + (size_t)r * H + kk * 32 + quad * 8);
        }
    }

    float bi[4][2];
#pragma unroll
    for (int p = 0; p < 4; ++p) {
        bi[p][0] = gb[k * H + 32 * p + l16];
        bi[p][1] = gb[k * H + 32 * p + 16 + l16];
    }
    bf16x8 bw[4];
#pragma unroll
    for (int kk = 0; kk < 4; ++kk)
        bw[kk] = *(const bf16x8*)(WRb + (size_t)((k * 4 + kk) * 64 + lane) * 8);

    for (int t = 0; t < 4; ++t) {
        if (t < 3) {
            int rb0 = rowbase + (t + 1) * 128;
#pragma unroll
            for (int rb = 0; rb < 2; ++rb) {
                int r = rb0 + rb * 16 + l16;
                if (r >= N) r = N - 1;
#pragma unroll
                for (int kk = 0; kk < 4; ++kk)
                    af[(t + 1) & 1][rb][kk] = *(const bf16x8*)(pxb + (size_t)r * H + kk * 32 + quad * 8);
            }
        }
        int row0 = rowbase + t * 128;
        f32x4 u0 = {}, u1 = {};
#pragma unroll
        for (int p = 0; p < 4; ++p) {
            f32x4 cacc[2][2] = {};
#pragma unroll
            for (int kk = 0; kk < 4; ++kk) {
                bf16x8 b0 = *(const bf16x8*)(Bs + (32 * p + l16) * 136 + kk * 32 + quad * 8);
                bf16x8 b1 = *(const bf16x8*)(Bs + (32 * p + 16 + l16) * 136 + kk * 32 + quad * 8);
#pragma unroll
                for (int rb = 0; rb < 2; ++rb) {
                    cacc[rb][0] = __builtin_amdgcn_mfma_f32_16x16x32_bf16(af[t & 1][rb][kk], b0, cacc[rb][0], 0, 0, 0);
                    cacc[rb][1] = __builtin_amdgcn_mfma_f32_16x16x32_bf16(af[t & 1][rb][kk], b1, cacc[rb][1], 0, 0, 0);
                }
            }
#pragma unroll
            for (int rb = 0; rb < 2; ++rb)
#pragma unroll
                for (int r = 0; r < 4; ++r) {
                    float lo = fmaxf(cacc[rb][0][r] + bi[p][0], 0.0f);
                    float hi = fmaxf(cacc[rb][1][r] + bi[p][1], 0.0f);
                    unsigned pk = (unsigned)f2bf(lo) | ((unsigned)f2bf(hi) << 16);
                    wl[(rb * 16 + quad * 4 + r) * 20 + l16] = pk;
                }
            bf16x8 a0 = *(const bf16x8*)(wl + l16 * 20 + quad * 4);
            bf16x8 a1 = *(const bf16x8*)(wl + (16 + l16) * 20 + quad * 4);
            u0 = __builtin_amdgcn_mfma_f32_16x16x32_bf16(a0, bw[p], u0, 0, 0, 0);
            u1 = __builtin_amdgcn_mfma_f32_16x16x32_bf16(a1, bw[p], u1, 0, 0, 0);
        }
        if (l16 < 4) {
#pragma unroll
            for (int r = 0; r < 4; ++r) {
                int ra = row0 + quad * 4 + r;
                int rb2 = ra + 16;
                if (ra < N) uall[(size_t)ra * 32 + k * 4 + l16] = u0[r];
                if (rb2 < N) uall[(size_t)rb2 * 32 + k * 4 + l16] = u1[r];
            }
        }
    }
}

// ---- aggregation 2 + softmax: v = dinv[i]*(sum us[j] + us[i]) + bias ----
__global__ void __launch_bounds__(256) k_out(const unsigned* __restrict__ us,
        const int2* __restrict__ rpse, const int* __restrict__ csrc,
        const float* __restrict__ dinv, const float* __restrict__ bias2,
        float* __restrict__ out, int N) {
    int lane = threadIdx.x & 63;
    int wv = threadIdx.x >> 6;
    int i = blockIdx.x * 4 + wv;
    if (i >= N) return;
    int grp = lane >> 2, sub = lane & 3;
    const unsigned* usb = us + sub * 4;
    int2 se = rpse[i];
    int s = se.x, e = se.y;
    float2 a0[4] = {{0.f,0.f},{0.f,0.f},{0.f,0.f},{0.f,0.f}};
    float2 a1[4] = {{0.f,0.f},{0.f,0.f},{0.f,0.f},{0.f,0.f}};
    for (int base = s; base < e; base += 64) {
        int el = base + lane;
        int j_l = (el < e) ? csrc[el] : N;
        int cnt = e - base; if (cnt > 64) cnt = 64;
        for (int t = 0; t < cnt; t += 32) {
            int jj0 = __shfl(j_l, t + grp);
            int jj1 = __shfl(j_l, t + 16 + grp);
            const uint4 v0 = *(const uint4*)(usb + (size_t)jj0 * 16);
            const uint4 v1 = *(const uint4*)(usb + (size_t)jj1 * 16);
            acc8(a0, v0); acc8(a1, v1);
        }
    }
    float acc[8];
#pragma unroll
    for (int r = 0; r < 4; ++r) {
        acc[2 * r] = a0[r].x + a1[r].x;
        acc[2 * r + 1] = a0[r].y + a1[r].y;
    }
#pragma unroll
    for (int r = 0; r < 8; ++r) {
        acc[r] += __shfl_xor(acc[r], 4);
        acc[r] += __shfl_xor(acc[r], 8);
        acc[r] += __shfl_xor(acc[r], 16);
        acc[r] += __shfl_xor(acc[r], 32);
    }
    if (grp == 0) {
        const uint4 sv = *(const uint4*)(usb + (size_t)i * 16);
        float d = dinv[i];
        float4 bA = *(const float4*)(bias2 + sub * 8);
        float4 bB = *(const float4*)(bias2 + sub * 8 + 4);
        float w0 = d * (acc[0] + bflo(sv.x)) + bA.x;
        float w1 = d * (acc[1] + bfhi(sv.x)) + bA.y;
        float w2 = d * (acc[2] + bflo(sv.y)) + bA.z;
        float w4 = d * (acc[4] + bflo(sv.z)) + bB.x;
        float w5 = d * (acc[5] + bfhi(sv.z)) + bB.y;
        float w6 = d * (acc[6] + bflo(sv.w)) + bB.z;
        auto wr = [&](int b, float v0, float v1, float v2) {
            int ck = (b < 5) ? 3 : 2;
            float mx = fmaxf(v0, v1);
            if (ck == 3) mx = fmaxf(mx, v2);
            float e0 = __expf(v0 - mx), e1 = __expf(v1 - mx);
            float e2 = (ck == 3) ? __expf(v2 - mx) : 0.0f;
            float inv = 1.0f / (e0 + e1 + e2);
            size_t bb = (b < 5) ? (size_t)b * 3 * N + (size_t)i * 3
                                : (size_t)15 * N + (size_t)(b - 5) * 2 * N + (size_t)i * 2;
            out[bb] = e0 * inv;
            out[bb + 1] = e1 * inv;
            if (ck == 3) out[bb + 2] = e2 * inv;
        };
        wr(sub * 2, w0, w1, w2);
        if (sub < 3) wr(sub * 2 + 1, w4, w5, w6);
    }
}

// ---- launch -------------------------------------------------------------
extern "C" void kernel_launch(void* const* d_in, const int* in_sizes, int n_in,
                              void* d_out, int out_size, void* d_ws, size_t ws_size,
                              hipStream_t stream) {
    (void)n_in; (void)out_size; (void)ws_size;
    const float* x   = (const float*)d_in[0];
    const int*   ei  = (const int*)d_in[1];
    const float* gw  = (const float*)d_in[2];
    const float* gb  = (const float*)d_in[3];
    const float* r3w = (const float*)d_in[4];
    const float* r3b = (const float*)d_in[5];
    const float* r2w = (const float*)d_in[6];
    const float* r2b = (const float*)d_in[7];
    float* out = (float*)d_out;
    int N = in_sizes[0] / H;   // 100000
    int E = in_sizes[1] / 2;   // 1600000
    int NB = (N + 255) >> 8;   // 391 buckets

    char* p = (char*)d_ws;
    auto alloc = [&](size_t bytes) {
        char* q = p;
        p += (bytes + 255) & ~(size_t)255;
        return q;
    };
    unsigned*       xs     = (unsigned*)alloc((size_t)(N + 1) * 64 * 4);
    unsigned*       pxb    = (unsigned*)alloc((size_t)N * 64 * 4);
    unsigned short* Wt     = (unsigned short*)alloc((size_t)7 * 16384 * 2);
    unsigned short* WRb    = (unsigned short*)alloc((size_t)14336 * 2);
    float*          bias2  = (float*)alloc(32 * 4);
    int*            gcur   = (int*)alloc(512 * 4);
    int*            tmp_e  = (int*)alloc((size_t)NB * CAP * 4);
    int2*           rpse   = (int2*)alloc((size_t)N * 8);
    float*          dinv   = (float*)alloc((size_t)N * 4);
    int*            csrc   = (int*)alloc((size_t)NB * CAP * 4);
    float*          uall   = (float*)alloc((size_t)N * 32 * 4);
    unsigned*       usb    = (unsigned*)alloc((size_t)(N + 1) * 16 * 4);

    hipMemsetAsync(gcur, 0, 512 * 4, stream);
    k_scatter<<<512, 256, 0, stream>>>(ei, gcur, tmp_e, E);
    k_csrAB<<<NB, 512, 0, stream>>>(tmp_e, gcur, rpse, dinv, csrc, N);
    int prep_threads = N * 64 + 64 + 114688 + 14368;
    k_prep<<<(prep_threads + 255) / 256, 256, 0, stream>>>(x, dinv, xs, N,
            gw, gb, r3w, r3b, r2w, r2b, Wt, WRb, bias2);
    k_px<<<(N + 3) / 4, 256, 0, stream>>>(xs, rpse, csrc, dinv, pxb, N);
    dim3 gg((N + 511) / 512, 7);
    k_gemm<<<gg, 256, 0, stream>>>((const unsigned short*)pxb, Wt, gb, WRb, uall, N);
    k_uscale<<<(N * 16 + 16 + 255) / 256, 256, 0, stream>>>(uall, dinv, usb, N);
    k_out<<<(N + 3) / 4, 256, 0, stream>>>(usb, rpse, csrc, dinv, bias2, out, N);
}